// Round 3
// baseline (153.748 us; speedup 1.0000x reference)
//
#include <hip/hip_runtime.h>
#include <hip/hip_bf16.h>
#include <hip/hip_fp8.h>
#include <stdint.h>

typedef float floatx4 __attribute__((ext_vector_type(4)));

#define B_    4096
#define D_    1024
#define C_    1000
#define CPAD  1024
#define NVALID (B_ + C_)    // 5096 valid columns
#define NSLOT 40            // 32 F-col-tiles + 8 center-col-tiles
#define TAU_INV 10.0f
#define EPS_    1e-8f

__device__ inline unsigned cvt4_fp8(float4 v) {
    __hip_fp8_e4m3 a(v.x), b(v.y), c(v.z), d(v.w);
    return (unsigned)a.__x | ((unsigned)b.__x << 8) | ((unsigned)c.__x << 16) | ((unsigned)d.__x << 24);
}

// ---------------- prep: cvt fp32->fp8, zero pad, class counts --------------
// grid 5111 x 256. Work map (g = global thread):
//   [0, 1048576)         : features cvt, float4 #g -> u32 fp8x4   (4096*1024/4)
//   [1048576, 1304576)   : centers  cvt, float4 #(g-1048576)      (1000*1024/4)
//   [1306624, 1308160)   : zero center pad rows, int4 (24*1024 B = 1536 int4)
// block 5110 computes counts[1024] via LDS atomics.
__global__ __launch_bounds__(256) void prep_kernel(
    const float* __restrict__ centers, const float* __restrict__ features,
    const int* __restrict__ targets,
    unsigned* __restrict__ Af8, unsigned* __restrict__ Cf8, int* __restrict__ counts)
{
    const int tid = threadIdx.x;
    const int g = blockIdx.x * 256 + tid;
    if (g < 1048576) {
        Af8[g] = cvt4_fp8(((const float4*)features)[g]);
    } else if (g < 1304576) {
        int i = g - 1048576;
        Cf8[i] = cvt4_fp8(((const float4*)centers)[i]);
    } else if (g >= 1306624 && g < 1308160) {
        int i = g - 1306624;                    // 0..1535
        int4 z = make_int4(0, 0, 0, 0);
        ((int4*)((uint8_t*)Cf8 + (size_t)C_ * D_))[i] = z;
    }
    if (blockIdx.x == 5110) {
        __shared__ int lc[CPAD];
        #pragma unroll
        for (int j = 0; j < 4; ++j) lc[tid * 4 + j] = 0;
        __syncthreads();
        for (int i = tid; i < B_; i += 256) atomicAdd(&lc[targets[i]], 1);
        __syncthreads();
        int4 o; o.x = lc[tid*4]; o.y = lc[tid*4+1]; o.z = lc[tid*4+2]; o.w = lc[tid*4+3];
        ((int4*)counts)[tid] = o;
    }
}

// ---------------- fused symmetric fp8 GEMM + dual-sided epilogue ------------
// K-loop: round-0 structure (single-buffer stage -> barrier -> compute),
// proven fastest of the three schedules tried (68 vs 84 vs 128 us).
// EPILOGUE CHANGE (this round's single variable): zero global atomics.
// Every (col-tile-slot, row) pair has a unique writer block:
//   row-side of (rt,ct):  slot ct,    rows of tile rt
//   mirror  of (rt,ct):   slot rt,    rows of tile ct      (rt < ct)
//   center   (rt,cc):     slot 32+cc, rows of tile rt
// so per-block partials go to pd/pp[40][4096] via plain coalesced stores.
// The cross-wave sum the atomics used to perform (waves 0/1 and 2/3 split the
// columns of a row; waves 0/2 and 1/3 split the rows of a column) is done in
// 4 KiB of reused K-loop LDS. finalize1 reduces the 40 slots per row.
// Old: ~1024 device-scope atomicAdds/block = 730k far-atomics, 47 MB of
// 64B-line write-through (the anomalous WRITE_SIZE=53.5 MB) + serialization.
#define GLD_LDS16(g, l) __builtin_amdgcn_global_load_lds( \
    (const __attribute__((address_space(1))) void*)(g),   \
    (__attribute__((address_space(3))) void*)(l), 16, 0, 0)

__global__ __launch_bounds__(256, 4) void gemm_epilogue(
    const uint8_t* __restrict__ Af8,   // [4096][1024] fp8 e4m3
    const uint8_t* __restrict__ Cf8,   // [1024][1024] fp8 (rows >= 1000 zero)
    const int*     __restrict__ counts,
    const int*     __restrict__ targets,
    float* __restrict__ pd, float* __restrict__ pp)   // [NSLOT][4096] partials
{
    __shared__ __align__(16) uint8_t ldsA[128 * 64];
    __shared__ __align__(16) uint8_t ldsB[128 * 64];

    const int tid  = threadIdx.x;
    const int wave = tid >> 6;
    const int lane = tid & 63;
    const int bid  = blockIdx.x;

    int rt, colTile, slotRow;
    const uint8_t* Bbase;
    bool mirror;
    if (bid < 528) {
        int idx = bid, r = 0;
        while (idx >= 32 - r) { idx -= 32 - r; ++r; }   // scalar, uniform
        rt = r;
        int ct = r + idx;
        colTile = ct * 128;
        Bbase = Af8 + (size_t)ct * 128 * D_;
        mirror = (ct != rt);
        slotRow = ct;
    } else {
        int m = bid - 528;
        rt = m >> 3;
        int cc = m & 7;
        colTile = B_ + cc * 128;
        Bbase = Cf8 + (size_t)cc * 128 * D_;
        mirror = false;
        slotRow = 32 + cc;
    }
    const int rowTile = rt * 128;

    // ---- staging map: 2 instrs per matrix per thread; instr j covers rows
    // (wave + 4j)*16 .. +15 (lane>>2 within), chunk (lane&3) XOR-permuted.
    const int r0 = wave * 16 + (lane >> 2);         // j = 0 local row
    const int r1 = r0 + 64;                          // j = 1 local row
    const int gc0 = ((lane & 3) ^ ((r0 >> 1) & 3)) * 16;
    const int gc1 = ((lane & 3) ^ ((r1 >> 1) & 3)) * 16;
    const uint8_t* gA0 = Af8 + (size_t)(rowTile + r0) * D_ + gc0;
    const uint8_t* gA1 = Af8 + (size_t)(rowTile + r1) * D_ + gc1;
    const uint8_t* gB0 = Bbase + (size_t)r0 * D_ + gc0;
    const uint8_t* gB1 = Bbase + (size_t)r1 * D_ + gc1;
    uint8_t* lA0 = &ldsA[wave * 1024];
    uint8_t* lA1 = &ldsA[(wave + 4) * 1024];
    uint8_t* lB0 = &ldsB[wave * 1024];
    uint8_t* lB1 = &ldsB[(wave + 4) * 1024];

    floatx4 acc[4][4] = {};

    const int wrow  = (wave >> 1) * 64;
    const int wcolw = (wave & 1) * 64;
    const int fr = lane & 15;
    const int fq = lane >> 4;
    // fragment LDS byte offsets within a row, per k-step s:
    const int sw = (fr >> 1) & 3;
    const int off_s0 = (((fq >> 1) ^ sw) * 16) + (fq & 1) * 8;          // s=0
    const int off_s1 = (((2 + (fq >> 1)) ^ sw) * 16) + (fq & 1) * 8;    // s=1

    for (int k0 = 0; k0 < D_; k0 += 64) {
        if (k0) __syncthreads();
        GLD_LDS16(gA0 + k0, lA0);
        GLD_LDS16(gA1 + k0, lA1);
        GLD_LDS16(gB0 + k0, lB0);
        GLD_LDS16(gB1 + k0, lB1);
        __syncthreads();

        #pragma unroll
        for (int s = 0; s < 2; ++s) {
            const int off = s ? off_s1 : off_s0;
            long af[4], bfv[4];
            #pragma unroll
            for (int ri = 0; ri < 4; ++ri)
                af[ri] = *(const long*)&ldsA[(wrow + ri * 16 + fr) * 64 + off];
            #pragma unroll
            for (int ci = 0; ci < 4; ++ci)
                bfv[ci] = *(const long*)&ldsB[(wcolw + ci * 16 + fr) * 64 + off];
            #pragma unroll
            for (int ri = 0; ri < 4; ++ri)
                #pragma unroll
                for (int ci = 0; ci < 4; ++ci)
                    acc[ri][ci] = __builtin_amdgcn_mfma_f32_16x16x32_fp8_fp8(
                        af[ri], bfv[ci], acc[ri][ci], 0, 0, 0);
        }
    }

    // ---- epilogue ----
    float wv[4]; int tcol[4]; int colg[4];
    #pragma unroll
    for (int ci = 0; ci < 4; ++ci) {
        int cg = colTile + wcolw + ci * 16 + fr;
        colg[ci] = cg;
        int cls = (cg < B_) ? targets[cg] : (cg - B_);
        tcol[ci] = cls;
        wv[ci] = (cg < NVALID) ? 1.f / (float)(counts[cls] + 1) : 0.f;
    }

    // LDS reduction scratch overlaid on ldsA (K-loop done after this barrier).
    float* red_rd = (float*)ldsA;          // [2][128] row-denom, idx0 = wave&1
    float* red_rp = red_rd + 256;          // [2][128] row-possum
    float* red_cd = red_rp + 256;          // [2][128] col-denom, idx0 = wave>>1
    float* red_cp = red_cd + 256;          // [2][128] col-possum
    __syncthreads();                       // all ds_reads of K-loop complete

    float dcol[4] = {0.f, 0.f, 0.f, 0.f};
    float pcol[4] = {0.f, 0.f, 0.f, 0.f};

    #pragma unroll
    for (int ri = 0; ri < 4; ++ri) {
        #pragma unroll
        for (int reg = 0; reg < 4; ++reg) {
            int lr = wrow + ri * 16 + fq * 4 + reg;               // local row 0..127
            int rowg = rowTile + lr;                               // C/D: row=(lane>>4)*4+reg
            int trow = targets[rowg];
            float wr = 1.f / (float)(counts[trow] + 1);
            float dsum = 0.f, psum = 0.f;
            #pragma unroll
            for (int ci = 0; ci < 4; ++ci) {
                float s = acc[ri][ci][reg] * TAU_INV;
                float e = __expf(s);
                dsum += wv[ci] * e;
                bool pos = (tcol[ci] == trow) && (colg[ci] != rowg);
                float gterm = pos ? (s + log1pf(EPS_ * __expf(-s))) : 0.f;   // log(exp(s)+eps)
                psum += gterm;
                if (mirror) { dcol[ci] += wr * e; pcol[ci] += gterm; }
            }
            #pragma unroll
            for (int m = 1; m < 16; m <<= 1) {
                dsum += __shfl_xor(dsum, m, 64);
                psum += __shfl_xor(psum, m, 64);
            }
            if (fr == 0) {       // lanes fq=0..3 hold the fr-sum for row lr
                red_rd[(wave & 1) * 128 + lr] = dsum;
                red_rp[(wave & 1) * 128 + lr] = psum;
            }
        }
    }

    if (mirror) {
        #pragma unroll
        for (int ci = 0; ci < 4; ++ci) {
            float d = dcol[ci], p = pcol[ci];
            d += __shfl_xor(d, 16, 64); d += __shfl_xor(d, 32, 64);
            p += __shfl_xor(p, 16, 64); p += __shfl_xor(p, 32, 64);
            if (fq == 0) {       // lanes fr=0..15 hold col sums for this wave's rows
                red_cd[(wave >> 1) * 128 + wcolw + ci * 16 + fr] = d;
                red_cp[(wave >> 1) * 128 + wcolw + ci * 16 + fr] = p;
            }
        }
    }

    __syncthreads();
    if (tid < 128) {
        float d = red_rd[tid] + red_rd[128 + tid];   // sum the two column-halves
        float p = red_rp[tid] + red_rp[128 + tid];
        pd[slotRow * B_ + rowTile + tid] = d;        // coalesced, unique writer
        pp[slotRow * B_ + rowTile + tid] = p;
        if (mirror) {
            float d2 = red_cd[tid] + red_cd[128 + tid];  // sum the two row-halves
            float p2 = red_cp[tid] + red_cp[128 + tid];
            pd[rt * B_ + colTile + tid] = d2;
            pp[rt * B_ + colTile + tid] = p2;
        }
    }
}

// ---------------- finalize1: reduce 40 slots/row -> per-block loss sum ------
__global__ __launch_bounds__(256) void finalize1(
    const float* __restrict__ pd, const float* __restrict__ pp,
    const int* __restrict__ counts, const int* __restrict__ targets,
    float* __restrict__ lossbuf)
{
    __shared__ float red[4];
    const int row = blockIdx.x * 256 + threadIdx.x;   // grid 16 x 256 = 4096
    float d = 0.f, p = 0.f;
    #pragma unroll
    for (int s = 0; s < NSLOT; ++s) {
        d += pd[s * B_ + row];
        p += pp[s * B_ + row];
    }
    float npos = (float)counts[targets[row]];
    float local = logf(d + EPS_) - p / npos;
    #pragma unroll
    for (int m = 1; m < 64; m <<= 1) local += __shfl_xor(local, m, 64);
    if ((threadIdx.x & 63) == 0) red[threadIdx.x >> 6] = local;
    __syncthreads();
    if (threadIdx.x == 0)
        lossbuf[blockIdx.x] = red[0] + red[1] + red[2] + red[3];
}

// ---------------- finalize2: mean over 16 block sums ------------------------
__global__ void finalize2(const float* __restrict__ lossbuf, float* __restrict__ out) {
    if (threadIdx.x == 0) {
        float s = 0.f;
        #pragma unroll
        for (int i = 0; i < 16; ++i) s += lossbuf[i];
        out[0] = s * (1.f / (float)B_);
    }
}

extern "C" void kernel_launch(void* const* d_in, const int* in_sizes, int n_in,
                              void* d_out, int out_size, void* d_ws, size_t ws_size,
                              hipStream_t stream) {
    const float* centers  = (const float*)d_in[0];   // [1000][1024]
    const float* features = (const float*)d_in[1];   // [4096][1024]
    const int*   targets  = (const int*)d_in[2];     // [4096]
    float* out = (float*)d_out;

    char* ws = (char*)d_ws;
    unsigned* Af8    = (unsigned*)(ws);                    // 4 MiB fp8
    unsigned* Cf8    = (unsigned*)(ws + 4194304);          // 1 MiB fp8 (rows 1000..1023 zeroed)
    int*    counts  = (int*)   (ws + 5242880);             // 1024 i32
    float*  pd      = (float*) (ws + 5246976);             // 40*4096 f32 = 640 KiB
    float*  pp      = (float*) (ws + 5902336);             // 40*4096 f32 = 640 KiB
    float*  lossbuf = (float*) (ws + 6557696);             // 16 f32

    hipLaunchKernelGGL(prep_kernel, dim3(5111), dim3(256), 0, stream,
                       centers, features, targets, Af8, Cf8, counts);
    hipLaunchKernelGGL(gemm_epilogue, dim3(784), dim3(256), 0, stream,
                       (const uint8_t*)Af8, (const uint8_t*)Cf8, counts, targets, pd, pp);
    hipLaunchKernelGGL(finalize1, dim3(16), dim3(256), 0, stream,
                       pd, pp, counts, targets, lossbuf);
    hipLaunchKernelGGL(finalize2, dim3(1), dim3(64), 0, stream, lossbuf, out);
}